// Round 1
// baseline (88.038 us; speedup 1.0000x reference)
//
#include <hip/hip_runtime.h>

// Mixture-of-64-tiny-experts: per sample b (524288):
//   h[s]    = tanhshrink(W1[s] @ x + b1[s])      (64 x 6->4)
//   o[s]    = tanh(W2[s] @ h[s] + b2[s])         (64 x 4->2)
//   g       = tanhshrink(Gw1 @ x + Gb1)          (6->6)
//   gate    = softmax(Gw2 @ g + Gb2)             (6->64)
//   out     = sum_s gate[s] * o[s]               ([B,2] fp32)
//
// Compute-bound (VALU + transcendental). Weights ~11.7KB, wave-uniform ->
// rely on compiler scalarization (s_load + FMA-with-SGPR-operand).

#define NSUB 64

__device__ __forceinline__ float fast_exp(float x) {
    // e^x = 2^(x * log2(e))
    return __builtin_amdgcn_exp2f(x * 1.4426950408889634f);
}

__device__ __forceinline__ float fast_tanh(float x) {
    // tanh(x) = 1 - 2/(e^(2x) + 1); e^(2x) = 2^(x * 2*log2(e))
    // x -> +inf: e -> inf, rcp -> 0, result 1.  x -> -inf: e -> 0, result -1.
    float e = __builtin_amdgcn_exp2f(x * 2.8853900817779268f);
    return 1.0f - 2.0f * __builtin_amdgcn_rcpf(e + 1.0f);
}

__global__ __launch_bounds__(256) void moe_kernel(
    const float* __restrict__ x,
    const float* __restrict__ W1, const float* __restrict__ b1,
    const float* __restrict__ W2, const float* __restrict__ b2,
    const float* __restrict__ Gw1, const float* __restrict__ Gb1,
    const float* __restrict__ Gw2, const float* __restrict__ Gb2,
    float* __restrict__ out)
{
    // Each thread handles 2 adjacent samples: 12 input floats = 3 float4.
    int t = blockIdx.x * blockDim.x + threadIdx.x;
    long base = (long)t * 12;

    const float4* xv = (const float4*)(x + base);
    float4 a0 = xv[0];
    float4 a1 = xv[1];
    float4 a2 = xv[2];
    float xa[6] = {a0.x, a0.y, a0.z, a0.w, a1.x, a1.y};
    float xb[6] = {a1.z, a1.w, a2.x, a2.y, a2.z, a2.w};

    // ---- gating hidden: g = tanhshrink(Gw1 @ x + Gb1), 6 values/sample ----
    float ga[6], gb[6];
#pragma unroll
    for (int j = 0; j < 6; ++j) {
        float bias = Gb1[j];
        float sa = bias, sb = bias;
#pragma unroll
        for (int i = 0; i < 6; ++i) {
            float w = Gw1[j * 6 + i];
            sa = fmaf(w, xa[i], sa);
            sb = fmaf(w, xb[i], sb);
        }
        ga[j] = sa - fast_tanh(sa);
        gb[j] = sb - fast_tanh(sb);
    }

    // ---- subnet loop: fold softmax numerator/denominator into accumulators ----
    float acc0a = 0.f, acc1a = 0.f, accEa = 0.f;
    float acc0b = 0.f, acc1b = 0.f, accEb = 0.f;

#pragma unroll 2
    for (int s = 0; s < NSUB; ++s) {
        const float* w1 = W1 + s * 24;  // [4][6]
        float ha[4], hb[4];
#pragma unroll
        for (int j = 0; j < 4; ++j) {
            float bias = b1[s * 4 + j];
            float sa = bias, sb = bias;
#pragma unroll
            for (int i = 0; i < 6; ++i) {
                float w = w1[j * 6 + i];
                sa = fmaf(w, xa[i], sa);
                sb = fmaf(w, xb[i], sb);
            }
            ha[j] = sa - fast_tanh(sa);   // tanhshrink
            hb[j] = sb - fast_tanh(sb);
        }

        float oa[2], ob[2];
#pragma unroll
        for (int o = 0; o < 2; ++o) {
            float bias = b2[s * 2 + o];
            float sa = bias, sb = bias;
#pragma unroll
            for (int j = 0; j < 4; ++j) {
                float w = W2[s * 8 + o * 4 + j];
                sa = fmaf(w, ha[j], sa);
                sb = fmaf(w, hb[j], sb);
            }
            oa[o] = fast_tanh(sa);
            ob[o] = fast_tanh(sb);
        }

        // gate logit (softmax applied via running numerator/denominator;
        // no max-subtraction: |logit| << 80, exp stays in fp32 range)
        float la = Gb2[s], lb = la;
#pragma unroll
        for (int j = 0; j < 6; ++j) {
            float w = Gw2[s * 6 + j];
            la = fmaf(w, ga[j], la);
            lb = fmaf(w, gb[j], lb);
        }
        float ea = fast_exp(la);
        float eb = fast_exp(lb);
        accEa += ea;
        accEb += eb;
        acc0a = fmaf(ea, oa[0], acc0a);
        acc1a = fmaf(ea, oa[1], acc1a);
        acc0b = fmaf(eb, ob[0], acc0b);
        acc1b = fmaf(eb, ob[1], acc1b);
    }

    float ra = __builtin_amdgcn_rcpf(accEa);
    float rb = __builtin_amdgcn_rcpf(accEb);
    float4 r;
    r.x = acc0a * ra;
    r.y = acc1a * ra;
    r.z = acc0b * rb;
    r.w = acc1b * rb;
    ((float4*)&out[(long)t * 4])[0] = r;
}

extern "C" void kernel_launch(void* const* d_in, const int* in_sizes, int n_in,
                              void* d_out, int out_size, void* d_ws, size_t ws_size,
                              hipStream_t stream) {
    const float* x   = (const float*)d_in[0];
    const float* W1  = (const float*)d_in[1];
    const float* b1  = (const float*)d_in[2];
    const float* W2  = (const float*)d_in[3];
    const float* b2  = (const float*)d_in[4];
    const float* Gw1 = (const float*)d_in[5];
    const float* Gb1 = (const float*)d_in[6];
    const float* Gw2 = (const float*)d_in[7];
    const float* Gb2 = (const float*)d_in[8];
    float* out = (float*)d_out;

    // 524288 samples, 2 per thread -> 262144 threads
    const int threads = 256;
    const int blocks = (524288 / 2) / threads;  // 1024
    moe_kernel<<<blocks, threads, 0, stream>>>(x, W1, b1, W2, b2, Gw1, Gb1, Gw2, Gb2, out);
}